// Round 1
// baseline (414.421 us; speedup 1.0000x reference)
//
#include <hip/hip_runtime.h>

typedef _Float16 half8 __attribute__((ext_vector_type(8)));
typedef _Float16 half4v __attribute__((ext_vector_type(4)));
typedef float f32x4 __attribute__((ext_vector_type(4)));
typedef unsigned int u32;

#define SEQ 2048
#define NTOK 4096
#define DM 1024
#define D3 3072
#define NHEAD 16
#define DHEAD 64
#define LN_EPS 1e-5f
#define SM_SCALE 0.125f

// ---------------- async global->LDS (16B per lane) ----------------
typedef const __attribute__((address_space(1))) u32* gas_ptr;
typedef __attribute__((address_space(3))) u32* las_ptr;
__device__ __forceinline__ void gld_lds16(const void* g, void* l) {
  __builtin_amdgcn_global_load_lds((gas_ptr)g, (las_ptr)l, 16, 0, 0);
}

// ---------------- LayerNorm + cast to f16 ----------------
__global__ __launch_bounds__(256) void ln_cast_kernel(
    const float* __restrict__ x, const float* __restrict__ g,
    const float* __restrict__ bta, _Float16* __restrict__ xn) {
  const int row = blockIdx.x;
  const int t = threadIdx.x;
  const float4 v = ((const float4*)(x + (size_t)row * DM))[t];
  float s = v.x + v.y + v.z + v.w;
#pragma unroll
  for (int m = 1; m < 64; m <<= 1) s += __shfl_xor(s, m, 64);
  __shared__ float red[4];
  const int wid = t >> 6, lane = t & 63;
  if (lane == 0) red[wid] = s;
  __syncthreads();
  const float mu = (red[0] + red[1] + red[2] + red[3]) * (1.0f / DM);
  const float dx = v.x - mu, dy = v.y - mu, dz = v.z - mu, dw = v.w - mu;
  float ss = dx * dx + dy * dy + dz * dz + dw * dw;
#pragma unroll
  for (int m = 1; m < 64; m <<= 1) ss += __shfl_xor(ss, m, 64);
  __syncthreads();
  if (lane == 0) red[wid] = ss;
  __syncthreads();
  const float var = (red[0] + red[1] + red[2] + red[3]) * (1.0f / DM);
  const float rstd = rsqrtf(var + LN_EPS);
  const float4 gg = ((const float4*)g)[t];
  const float4 bb = ((const float4*)bta)[t];
  half4v o;
  o[0] = (_Float16)(dx * rstd * gg.x + bb.x);
  o[1] = (_Float16)(dy * rstd * gg.y + bb.y);
  o[2] = (_Float16)(dz * rstd * gg.z + bb.z);
  o[3] = (_Float16)(dw * rstd * gg.w + bb.w);
  *(half4v*)(xn + (size_t)row * DM + t * 4) = o;
}

// ---------------- plain f32 -> f16 cast (float4 granularity) ----------------
__global__ __launch_bounds__(256) void cast_f16_kernel(const float* __restrict__ in,
                                                       _Float16* __restrict__ out) {
  const int i = blockIdx.x * 256 + threadIdx.x;
  const float4 v = ((const float4*)in)[i];
  half4v o;
  o[0] = (_Float16)v.x; o[1] = (_Float16)v.y;
  o[2] = (_Float16)v.z; o[3] = (_Float16)v.w;
  ((half4v*)out)[i] = o;
}

// ---------------- transpose + cast: W[K][Nc] f32 -> WT[Nc][K] f16 ----------------
__global__ __launch_bounds__(256) void transpose_cast_kernel(const float* __restrict__ W,
                                                             _Float16* __restrict__ WT,
                                                             int K, int Nc) {
  __shared__ float tile[64][65];
  const int n0 = blockIdx.x * 64, k0 = blockIdx.y * 64;
  const int t = threadIdx.x;
  const int c = t & 63;
#pragma unroll
  for (int i = 0; i < 16; i++) {
    const int r = (t >> 6) * 16 + i;
    tile[r][c] = W[(size_t)(k0 + r) * Nc + n0 + c];
  }
  __syncthreads();
#pragma unroll
  for (int i = 0; i < 16; i++) {
    const int n = (t >> 6) * 16 + i;
    WT[(size_t)(n0 + n) * K + k0 + c] = (_Float16)tile[c][n];
  }
}

// ---------------- GEMM: C[M,N] = A[M,K] * BT[N,K]^T, f16 in, f32 accum ----------------
// m97 structure: 128x128 tile, BK=32, 4 waves (2x2), global_load_lds staging.
// OUTMODE 0: f16 store to Ch. OUTMODE 1: f32 + bias store to Cf.
template <int OUTMODE>
__global__ __launch_bounds__(256) void gemm_nt_kernel(
    const _Float16* __restrict__ A, const _Float16* __restrict__ BT,
    _Float16* __restrict__ Ch, float* __restrict__ Cf,
    const float* __restrict__ bias, int M, int Nn, int K) {
  __shared__ _Float16 As[128 * 32];
  __shared__ _Float16 Bs[128 * 32];
  const int t = threadIdx.x;
  const int wid = t >> 6, lane = t & 63, lo = lane & 15, hi = lane >> 4;
  const int wm = wid >> 1, wn = wid & 1;
  const int m0 = blockIdx.y * 128, n0 = blockIdx.x * 128;

  f32x4 zero;
  zero[0] = 0.f; zero[1] = 0.f; zero[2] = 0.f; zero[3] = 0.f;
  f32x4 acc[4][4];
#pragma unroll
  for (int i = 0; i < 4; i++)
#pragma unroll
    for (int j = 0; j < 4; j++) acc[i][j] = zero;

  // staging geometry: per issue j (0,1), thread t covers row j*64 + (t>>2), kchunk (t&3)*8
  const int rowA = t >> 2;
  const int kcol = (t & 3) * 8;
  const _Float16* gA = A + (size_t)(m0 + rowA) * K + kcol;
  const _Float16* gB = BT + (size_t)(n0 + rowA) * K + kcol;

  for (int k0 = 0; k0 < K; k0 += 32) {
#pragma unroll
    for (int j = 0; j < 2; j++) {
      gld_lds16(gA + (size_t)(j * 64) * K + k0, As + j * 2048 + wid * 512);
      gld_lds16(gB + (size_t)(j * 64) * K + k0, Bs + j * 2048 + wid * 512);
    }
    __syncthreads();  // drains vmcnt (compiler emits vmcnt(0) before barrier)
    half8 af[4], bf[4];
#pragma unroll
    for (int i = 0; i < 4; i++) {
      af[i] = *(const half8*)(As + (wm * 64 + i * 16 + lo) * 32 + hi * 8);
      bf[i] = *(const half8*)(Bs + (wn * 64 + i * 16 + lo) * 32 + hi * 8);
    }
#pragma unroll
    for (int i = 0; i < 4; i++)
#pragma unroll
      for (int j = 0; j < 4; j++)
        acc[i][j] = __builtin_amdgcn_mfma_f32_16x16x32_f16(af[i], bf[j], acc[i][j], 0, 0, 0);
    __syncthreads();  // before next-stage overwrite
  }

  // epilogue: D[i][j]: row = 4*hi + r, col = lo  (verified m89 layout)
#pragma unroll
  for (int i = 0; i < 4; i++)
#pragma unroll
    for (int j = 0; j < 4; j++)
#pragma unroll
      for (int r = 0; r < 4; r++) {
        const int row = m0 + wm * 64 + i * 16 + 4 * hi + r;
        const int col = n0 + wn * 64 + j * 16 + lo;
        const float vv = acc[i][j][r];
        if (OUTMODE == 1)
          Cf[(size_t)row * Nn + col] = vv + bias[col];
        else
          Ch[(size_t)row * Nn + col] = (_Float16)vv;
      }
}

// ---------------- fused flash attention over two value streams ----------------
// grid: (SEQ/128, B*H). block: 256 = 4 waves; wave w owns q rows [bx*128 + w*32, +32)
__global__ __launch_bounds__(256) void attn_kernel(
    const _Float16* __restrict__ qkvm,  // [NTOK][3072]: q | k | v per head
    const _Float16* __restrict__ avm,   // [NTOK][1024]
    _Float16* __restrict__ xctx, _Float16* __restrict__ yctx) {
  __shared__ _Float16 Kl[64 * 72];    // K tile [key][d], padded
  __shared__ _Float16 Vt[64 * 72];    // V^T tile [d][key], padded
  __shared__ _Float16 AVt[64 * 72];   // AV^T tile [d][key], padded
  __shared__ _Float16 Pl[4][32 * 72]; // per-wave P [qrow][key], padded

  const int t = threadIdx.x;
  const int wid = t >> 6, lane = t & 63, lo = lane & 15, hi = lane >> 4;
  const int bh = blockIdx.y;
  const int b = bh >> 4, h = bh & 15;
  const int q0 = blockIdx.x * 128 + wid * 32;
  const size_t tokbase = (size_t)b * SEQ;

  // Q fragments in registers: qf[rg][kc]: Q[q0+rg*16+lo][kc*32 + hi*8 .. +7]
  half8 qf[2][2];
#pragma unroll
  for (int rg = 0; rg < 2; rg++)
#pragma unroll
    for (int kc = 0; kc < 2; kc++)
      qf[rg][kc] = *(const half8*)(qkvm + (tokbase + q0 + rg * 16 + lo) * D3 +
                                   h * DHEAD + kc * 32 + hi * 8);

  f32x4 zero;
  zero[0] = 0.f; zero[1] = 0.f; zero[2] = 0.f; zero[3] = 0.f;
  f32x4 accx[2][4], accy[2][4];
  float mst[2][4], lst[2][4];
#pragma unroll
  for (int rg = 0; rg < 2; rg++)
#pragma unroll
    for (int j = 0; j < 4; j++) {
      accx[rg][j] = zero; accy[rg][j] = zero;
      mst[rg][j] = -3.0e38f; lst[rg][j] = 0.0f;
    }

  for (int kv0 = 0; kv0 < SEQ; kv0 += 64) {
    // ---- stage K (row-major) and V/AV (transposed) into LDS ----
#pragma unroll
    for (int c0 = 0; c0 < 2; c0++) {
      const int c = t + c0 * 256;
      const int key = c >> 3, dc = c & 7;
      const size_t tok = tokbase + kv0 + key;
      const half8 kv = *(const half8*)(qkvm + tok * D3 + DM + h * DHEAD + dc * 8);
      *(half8*)(Kl + key * 72 + dc * 8) = kv;
      const half8 vv = *(const half8*)(qkvm + tok * D3 + 2 * DM + h * DHEAD + dc * 8);
      const half8 av = *(const half8*)(avm + tok * DM + h * DHEAD + dc * 8);
#pragma unroll
      for (int jj = 0; jj < 8; jj++) {
        Vt[(dc * 8 + jj) * 72 + key] = vv[jj];
        AVt[(dc * 8 + jj) * 72 + key] = av[jj];
      }
    }
    __syncthreads();

    // ---- S = Q K^T : s[rg][kg], D-layout row=4*hi+r, col(key)=lo ----
    f32x4 s[2][4];
#pragma unroll
    for (int kg = 0; kg < 4; kg++) {
      const half8 bk0 = *(const half8*)(Kl + (kg * 16 + lo) * 72 + hi * 8);
      const half8 bk1 = *(const half8*)(Kl + (kg * 16 + lo) * 72 + 32 + hi * 8);
#pragma unroll
      for (int rg = 0; rg < 2; rg++) {
        f32x4 z = __builtin_amdgcn_mfma_f32_16x16x32_f16(qf[rg][0], bk0, zero, 0, 0, 0);
        s[rg][kg] = __builtin_amdgcn_mfma_f32_16x16x32_f16(qf[rg][1], bk1, z, 0, 0, 0);
      }
    }
#pragma unroll
    for (int rg = 0; rg < 2; rg++)
#pragma unroll
      for (int kg = 0; kg < 4; kg++) s[rg][kg] *= SM_SCALE;

    // ---- online softmax; write P tile (f16) to per-wave LDS ----
#pragma unroll
    for (int rg = 0; rg < 2; rg++)
#pragma unroll
      for (int r = 0; r < 4; r++) {
        float tm = fmaxf(fmaxf(s[rg][0][r], s[rg][1][r]),
                         fmaxf(s[rg][2][r], s[rg][3][r]));
#pragma unroll
        for (int msk = 1; msk < 16; msk <<= 1) tm = fmaxf(tm, __shfl_xor(tm, msk, 64));
        const float mn = fmaxf(mst[rg][r], tm);
        const float fc = expf(mst[rg][r] - mn);
        mst[rg][r] = mn;
        float rs = 0.0f;
#pragma unroll
        for (int kg = 0; kg < 4; kg++) {
          const float p = expf(s[rg][kg][r] - mn);
          rs += p;
          Pl[wid][(rg * 16 + 4 * hi + r) * 72 + kg * 16 + lo] = (_Float16)p;
        }
#pragma unroll
        for (int msk = 1; msk < 16; msk <<= 1) rs += __shfl_xor(rs, msk, 64);
        lst[rg][r] = lst[rg][r] * fc + rs;
#pragma unroll
        for (int ng = 0; ng < 4; ng++) {
          accx[rg][ng][r] *= fc;
          accy[rg][ng][r] *= fc;
        }
      }

    // ---- PV for both value streams ----
#pragma unroll
    for (int kk = 0; kk < 2; kk++) {
      half8 pa[2];
#pragma unroll
      for (int rg = 0; rg < 2; rg++)
        pa[rg] = *(const half8*)(&Pl[wid][(rg * 16 + lo) * 72 + kk * 32 + hi * 8]);
#pragma unroll
      for (int ng = 0; ng < 4; ng++) {
        const half8 bv = *(const half8*)(Vt + (ng * 16 + lo) * 72 + kk * 32 + hi * 8);
        const half8 ba = *(const half8*)(AVt + (ng * 16 + lo) * 72 + kk * 32 + hi * 8);
#pragma unroll
        for (int rg = 0; rg < 2; rg++) {
          accx[rg][ng] = __builtin_amdgcn_mfma_f32_16x16x32_f16(pa[rg], bv, accx[rg][ng], 0, 0, 0);
          accy[rg][ng] = __builtin_amdgcn_mfma_f32_16x16x32_f16(pa[rg], ba, accy[rg][ng], 0, 0, 0);
        }
      }
    }
    __syncthreads();
  }

  // ---- normalize and store ctx (f16) ----
#pragma unroll
  for (int rg = 0; rg < 2; rg++)
#pragma unroll
    for (int r = 0; r < 4; r++) {
      const float inv = 1.0f / lst[rg][r];
      const size_t tok = tokbase + q0 + rg * 16 + 4 * hi + r;
#pragma unroll
      for (int ng = 0; ng < 4; ng++) {
        const int col = h * DHEAD + ng * 16 + lo;
        xctx[tok * DM + col] = (_Float16)(accx[rg][ng][r] * inv);
        yctx[tok * DM + col] = (_Float16)(accy[rg][ng][r] * inv);
      }
    }
}

// ---------------- launch ----------------
extern "C" void kernel_launch(void* const* d_in, const int* in_sizes, int n_in,
                              void* d_out, int out_size, void* d_ws, size_t ws_size,
                              hipStream_t stream) {
  const float* x      = (const float*)d_in[0];
  const float* y      = (const float*)d_in[1];
  const float* ln_g   = (const float*)d_in[2];
  const float* ln_b   = (const float*)d_in[3];
  const float* w_qkv  = (const float*)d_in[4];
  const float* w_av   = (const float*)d_in[5];
  const float* w_out  = (const float*)d_in[6];
  const float* b_out  = (const float*)d_in[7];
  const float* w_yout = (const float*)d_in[8];
  const float* b_yout = (const float*)d_in[9];
  float* out = (float*)d_out;

  // workspace layout (f16 elements), total ~79.7 MB
  _Float16* ws     = (_Float16*)d_ws;
  _Float16* xn     = ws;                    // 4096*1024
  _Float16* yh     = xn + 4194304;          // 4096*1024
  _Float16* wqkvT  = yh + 4194304;          // 3072*1024
  _Float16* wavT   = wqkvT + 3145728;       // 1024*1024
  _Float16* woutT  = wavT + 1048576;        // 1024*1024
  _Float16* wyoutT = woutT + 1048576;       // 1024*1024
  _Float16* qkvm   = wyoutT + 1048576;      // 4096*3072
  _Float16* avm    = qkvm + 12582912;       // 4096*1024
  _Float16* xc     = avm + 4194304;         // 4096*1024
  _Float16* yc     = xc + 4194304;          // 4096*1024

  ln_cast_kernel<<<NTOK, 256, 0, stream>>>(x, ln_g, ln_b, xn);
  cast_f16_kernel<<<4096, 256, 0, stream>>>(y, yh);
  transpose_cast_kernel<<<dim3(48, 16), 256, 0, stream>>>(w_qkv, wqkvT, 1024, 3072);
  transpose_cast_kernel<<<dim3(16, 16), 256, 0, stream>>>(w_av, wavT, 1024, 1024);
  transpose_cast_kernel<<<dim3(16, 16), 256, 0, stream>>>(w_out, woutT, 1024, 1024);
  transpose_cast_kernel<<<dim3(16, 16), 256, 0, stream>>>(w_yout, wyoutT, 1024, 1024);

  gemm_nt_kernel<0><<<dim3(24, 32), 256, 0, stream>>>(xn, wqkvT, qkvm, nullptr, nullptr, 4096, 3072, 1024);
  gemm_nt_kernel<0><<<dim3(8, 32), 256, 0, stream>>>(yh, wavT, avm, nullptr, nullptr, 4096, 1024, 1024);

  attn_kernel<<<dim3(16, 32), 256, 0, stream>>>(qkvm, avm, xc, yc);

  gemm_nt_kernel<1><<<dim3(8, 32), 256, 0, stream>>>(xc, woutT, nullptr, out, b_out, 4096, 1024, 1024);
  gemm_nt_kernel<1><<<dim3(8, 32), 256, 0, stream>>>(yc, wyoutT, nullptr, out + 4194304, b_yout, 4096, 1024, 1024);
}

// Round 2
// 262.373 us; speedup vs baseline: 1.5795x; 1.5795x over previous
//
#include <hip/hip_runtime.h>

typedef _Float16 half8 __attribute__((ext_vector_type(8)));
typedef _Float16 half4v __attribute__((ext_vector_type(4)));
typedef float f32x4 __attribute__((ext_vector_type(4)));
typedef unsigned int u32;

#define SEQ 2048
#define NTOK 4096
#define DM 1024
#define QKS 2048
#define NHEAD 16
#define DHEAD 64
#define LN_EPS 1e-5f
#define LOG2E_SCALE 0.18033688f  // 0.125 * log2(e)

// ---------------- async global->LDS (16B per lane) ----------------
typedef const __attribute__((address_space(1))) u32* gas_ptr;
typedef __attribute__((address_space(3))) u32* las_ptr;
__device__ __forceinline__ void gld_lds16(const void* g, void* l) {
  __builtin_amdgcn_global_load_lds((gas_ptr)g, (las_ptr)l, 16, 0, 0);
}

// ---------------- LayerNorm + cast to f16 ----------------
__global__ __launch_bounds__(256) void ln_cast_kernel(
    const float* __restrict__ x, const float* __restrict__ g,
    const float* __restrict__ bta, _Float16* __restrict__ xn) {
  const int row = blockIdx.x;
  const int t = threadIdx.x;
  const float4 v = ((const float4*)(x + (size_t)row * DM))[t];
  float s = v.x + v.y + v.z + v.w;
#pragma unroll
  for (int m = 1; m < 64; m <<= 1) s += __shfl_xor(s, m, 64);
  __shared__ float red[4];
  const int wid = t >> 6, lane = t & 63;
  if (lane == 0) red[wid] = s;
  __syncthreads();
  const float mu = (red[0] + red[1] + red[2] + red[3]) * (1.0f / DM);
  const float dx = v.x - mu, dy = v.y - mu, dz = v.z - mu, dw = v.w - mu;
  float ss = dx * dx + dy * dy + dz * dz + dw * dw;
#pragma unroll
  for (int m = 1; m < 64; m <<= 1) ss += __shfl_xor(ss, m, 64);
  __syncthreads();
  if (lane == 0) red[wid] = ss;
  __syncthreads();
  const float var = (red[0] + red[1] + red[2] + red[3]) * (1.0f / DM);
  const float rstd = rsqrtf(var + LN_EPS);
  const float4 gg = ((const float4*)g)[t];
  const float4 bb = ((const float4*)bta)[t];
  half4v o;
  o[0] = (_Float16)(dx * rstd * gg.x + bb.x);
  o[1] = (_Float16)(dy * rstd * gg.y + bb.y);
  o[2] = (_Float16)(dz * rstd * gg.z + bb.z);
  o[3] = (_Float16)(dw * rstd * gg.w + bb.w);
  *(half4v*)(xn + (size_t)row * DM + t * 4) = o;
}

// ---------------- plain f32 -> f16 cast ----------------
__global__ __launch_bounds__(256) void cast_f16_kernel(const float* __restrict__ in,
                                                       _Float16* __restrict__ out) {
  const int i = blockIdx.x * 256 + threadIdx.x;
  const float4 v = ((const float4*)in)[i];
  half4v o;
  o[0] = (_Float16)v.x; o[1] = (_Float16)v.y;
  o[2] = (_Float16)v.z; o[3] = (_Float16)v.w;
  ((half4v*)out)[i] = o;
}

// ---------------- transpose + cast: W[K][Nc] f32 -> WT[Nc][K] f16 ----------------
__global__ __launch_bounds__(256) void transpose_cast_kernel(const float* __restrict__ W,
                                                             _Float16* __restrict__ WT,
                                                             int K, int Nc) {
  __shared__ float tile[64][65];
  const int n0 = blockIdx.x * 64, k0 = blockIdx.y * 64;
  const int t = threadIdx.x;
  const int c = t & 63;
#pragma unroll
  for (int i = 0; i < 16; i++) {
    const int r = (t >> 6) * 16 + i;
    tile[r][c] = W[(size_t)(k0 + r) * Nc + n0 + c];
  }
  __syncthreads();
#pragma unroll
  for (int i = 0; i < 16; i++) {
    const int n = (t >> 6) * 16 + i;
    WT[(size_t)(n0 + n) * K + k0 + c] = (_Float16)tile[c][n];
  }
}

// ---------------- fused-pair GEMM: C = A[M,1024] * BT[N,1024]^T ----------------
// Two independent problems in one launch (part decoded from blockIdx).
// OUTMODE 0: f16 store; tiles with n0>=trbase store TRANSPOSED into Ct
//            laid out [bh][d][tok] (bh=(row>>11)*16 + (col-trbase)>>6).
// OUTMODE 1: f32 + bias store.
template <int OUTMODE>
__global__ __launch_bounds__(256) void gemm2_kernel(
    const _Float16* __restrict__ A0, const _Float16* __restrict__ B0,
    _Float16* C0, float* F0, const float* bias0, _Float16* T0, int trbase0, int cstr0,
    int nbx0, int nblk0,
    const _Float16* __restrict__ A1, const _Float16* __restrict__ B1,
    _Float16* C1, float* F1, const float* bias1, _Float16* T1, int trbase1, int cstr1,
    int nbx1) {
  __shared__ _Float16 As[128 * 32];
  __shared__ _Float16 Bs[128 * 32];
  // bijective XCD swizzle (grid % 8 == 0)
  int id = ((blockIdx.x & 7) * (gridDim.x >> 3)) + (blockIdx.x >> 3);
  const _Float16 *A, *BT;
  _Float16* Ch; float* Cf; const float* bias; _Float16* Ct;
  int trbase, cstr, nbx;
  if (id < nblk0) { A = A0; BT = B0; Ch = C0; Cf = F0; bias = bias0; Ct = T0; trbase = trbase0; cstr = cstr0; nbx = nbx0; }
  else { id -= nblk0; A = A1; BT = B1; Ch = C1; Cf = F1; bias = bias1; Ct = T1; trbase = trbase1; cstr = cstr1; nbx = nbx1; }
  const int bx = id % nbx, by = id / nbx;
  const int t = threadIdx.x;
  const int wid = t >> 6, lane = t & 63, lo = lane & 15, hi = lane >> 4;
  const int wm = wid >> 1, wn = wid & 1;
  const int m0 = by * 128, n0 = bx * 128;
  const int K = 1024;

  f32x4 zero;
  zero[0] = 0.f; zero[1] = 0.f; zero[2] = 0.f; zero[3] = 0.f;
  f32x4 acc[4][4];
#pragma unroll
  for (int i = 0; i < 4; i++)
#pragma unroll
    for (int j = 0; j < 4; j++) acc[i][j] = zero;

  const int rowA = t >> 2;
  const int kcol = (t & 3) * 8;
  const _Float16* gA = A + (size_t)(m0 + rowA) * K + kcol;
  const _Float16* gB = BT + (size_t)(n0 + rowA) * K + kcol;

  for (int k0 = 0; k0 < K; k0 += 32) {
#pragma unroll
    for (int j = 0; j < 2; j++) {
      gld_lds16(gA + (size_t)(j * 64) * K + k0, As + j * 2048 + wid * 512);
      gld_lds16(gB + (size_t)(j * 64) * K + k0, Bs + j * 2048 + wid * 512);
    }
    __syncthreads();
    half8 af[4], bf[4];
#pragma unroll
    for (int i = 0; i < 4; i++) {
      af[i] = *(const half8*)(As + (wm * 64 + i * 16 + lo) * 32 + hi * 8);
      bf[i] = *(const half8*)(Bs + (wn * 64 + i * 16 + lo) * 32 + hi * 8);
    }
#pragma unroll
    for (int i = 0; i < 4; i++)
#pragma unroll
      for (int j = 0; j < 4; j++)
        acc[i][j] = __builtin_amdgcn_mfma_f32_16x16x32_f16(af[i], bf[j], acc[i][j], 0, 0, 0);
    __syncthreads();
  }

  if (OUTMODE == 1) {
#pragma unroll
    for (int i = 0; i < 4; i++)
#pragma unroll
      for (int j = 0; j < 4; j++)
#pragma unroll
        for (int r = 0; r < 4; r++) {
          const int row = m0 + wm * 64 + i * 16 + 4 * hi + r;
          const int col = n0 + wn * 64 + j * 16 + lo;
          Cf[(size_t)row * cstr + col] = acc[i][j][r] + bias[col];
        }
  } else if (n0 >= trbase) {
#pragma unroll
    for (int i = 0; i < 4; i++)
#pragma unroll
      for (int j = 0; j < 4; j++)
#pragma unroll
        for (int r = 0; r < 4; r++) {
          const int row = m0 + wm * 64 + i * 16 + 4 * hi + r;
          const int coff = n0 + wn * 64 + j * 16 + lo - trbase;
          Ct[(((size_t)((row >> 11) << 4) + (coff >> 6)) * 64 + (coff & 63)) * SEQ +
             (row & (SEQ - 1))] = (_Float16)acc[i][j][r];
        }
  } else {
#pragma unroll
    for (int i = 0; i < 4; i++)
#pragma unroll
      for (int j = 0; j < 4; j++)
#pragma unroll
        for (int r = 0; r < 4; r++) {
          const int row = m0 + wm * 64 + i * 16 + 4 * hi + r;
          const int col = n0 + wn * 64 + j * 16 + lo;
          Ch[(size_t)row * cstr + col] = (_Float16)acc[i][j][r];
        }
  }
}

// ---------------- fused flash attention, two value streams ----------------
// 1-D grid of 512 blocks, XCD-mapped; block = 4 waves, wave owns 32 q-rows.
// LDS tiles are UNPADDED [64][64] with XOR chunk swizzle (chunk ^= row&7),
// staged via global_load_lds with pre-swizzled global source addresses.
__global__ __launch_bounds__(256) void attn_kernel(
    const _Float16* __restrict__ qkvm,  // [NTOK][2048]: q | k
    const _Float16* __restrict__ vt,    // [32][64][SEQ]
    const _Float16* __restrict__ avt,   // [32][64][SEQ]
    _Float16* __restrict__ xctx, _Float16* __restrict__ yctx) {
  __shared__ _Float16 Kl[2][4096];
  __shared__ _Float16 Vl[2][4096];
  __shared__ _Float16 Al[2][4096];
  __shared__ _Float16 Pl[4][2048];

  const int t = threadIdx.x;
  const int wid = t >> 6, lane = t & 63, lo = lane & 15, hi = lane >> 4;
  const int l7 = lane & 7;
  // XCD mapping: 64 blocks per XCD -> 4 heads per XCD (KV fits its L2)
  const int id = blockIdx.x;
  const int bh = ((id & 7) << 2) + ((id >> 3) >> 4);
  const int qt = (id >> 3) & 15;
  const int b = bh >> 4, h = bh & 15;
  const int q0 = qt * 128 + wid * 32;
  const size_t tokbase = (size_t)b * SEQ;
  const _Float16* vbase = vt + (size_t)bh * DHEAD * SEQ;
  const _Float16* abase = avt + (size_t)bh * DHEAD * SEQ;

  half8 qf[2][2];
#pragma unroll
  for (int rg = 0; rg < 2; rg++)
#pragma unroll
    for (int kc = 0; kc < 2; kc++)
      qf[rg][kc] = *(const half8*)(qkvm + (tokbase + q0 + rg * 16 + lo) * QKS +
                                   h * DHEAD + kc * 32 + hi * 8);

  f32x4 zero;
  zero[0] = 0.f; zero[1] = 0.f; zero[2] = 0.f; zero[3] = 0.f;
  f32x4 accx[2][4], accy[2][4];
  float mst[2][4], lst[2][4];
#pragma unroll
  for (int rg = 0; rg < 2; rg++)
#pragma unroll
    for (int j = 0; j < 4; j++) {
      accx[rg][j] = zero; accy[rg][j] = zero;
      mst[rg][j] = -3.0e38f; lst[rg][j] = 0.0f;
    }

  const int skey = t >> 3;  // 0..31
  const int sc7 = t & 7;

#define STAGE(kv0, bsel)                                                          \
  do {                                                                            \
    _Pragma("unroll") for (int j = 0; j < 2; j++) {                               \
      const int key = skey + j * 32;                                              \
      const int cs = ((sc7 ^ (key & 7)) << 3);                                    \
      gld_lds16(qkvm + (tokbase + (kv0) + key) * QKS + DM + h * DHEAD + cs,       \
                &Kl[bsel][j * 2048 + wid * 512]);                                 \
      gld_lds16(vbase + (size_t)key * SEQ + (kv0) + cs,                           \
                &Vl[bsel][j * 2048 + wid * 512]);                                 \
      gld_lds16(abase + (size_t)key * SEQ + (kv0) + cs,                           \
                &Al[bsel][j * 2048 + wid * 512]);                                 \
    }                                                                             \
  } while (0)

  STAGE(0, 0);
  int bsel = 0;
  for (int tt = 0; tt < SEQ / 64; tt++) {
    __syncthreads();  // tile tt staged (vmcnt drained by barrier)
    if (tt + 1 < SEQ / 64) STAGE((tt + 1) * 64, bsel ^ 1);
    const _Float16* Kb = Kl[bsel];
    const _Float16* Vb = Vl[bsel];
    const _Float16* Ab = Al[bsel];
    _Float16* Pw = Pl[wid];

    // ---- S = Q K^T ----
    f32x4 s[2][4];
#pragma unroll
    for (int kg = 0; kg < 4; kg++) {
      const int kr = (kg * 16 + lo) * 64;
      const half8 bk0 = *(const half8*)(Kb + kr + ((hi ^ l7) << 3));
      const half8 bk1 = *(const half8*)(Kb + kr + (((4 | hi) ^ l7) << 3));
#pragma unroll
      for (int rg = 0; rg < 2; rg++) {
        f32x4 z = __builtin_amdgcn_mfma_f32_16x16x32_f16(qf[rg][0], bk0, zero, 0, 0, 0);
        s[rg][kg] = __builtin_amdgcn_mfma_f32_16x16x32_f16(qf[rg][1], bk1, z, 0, 0, 0);
      }
    }

    // ---- online softmax (scale folded into exp2 fma) ----
#pragma unroll
    for (int rg = 0; rg < 2; rg++)
#pragma unroll
      for (int r = 0; r < 4; r++) {
        float tm = fmaxf(fmaxf(s[rg][0][r], s[rg][1][r]),
                         fmaxf(s[rg][2][r], s[rg][3][r]));
#pragma unroll
        for (int m = 1; m < 16; m <<= 1) tm = fmaxf(tm, __shfl_xor(tm, m, 64));
        const float mo = mst[rg][r];
        const float mn = fmaxf(mo, tm);
        mst[rg][r] = mn;
        const float fc = exp2f((mo - mn) * LOG2E_SCALE);
        const float mC = mn * LOG2E_SCALE;
        float rs = 0.f;
        const int prow = rg * 16 + 4 * hi + r;
        const int pr7 = prow & 7;
#pragma unroll
        for (int kg = 0; kg < 4; kg++) {
          const float p = exp2f(fmaf(s[rg][kg][r], LOG2E_SCALE, -mC));
          rs += p;
          Pw[prow * 64 + (((kg * 2 + (lo >> 3)) ^ pr7) << 3) + l7] = (_Float16)p;
        }
#pragma unroll
        for (int m = 1; m < 16; m <<= 1) rs += __shfl_xor(rs, m, 64);
        lst[rg][r] = lst[rg][r] * fc + rs;
#pragma unroll
        for (int ng = 0; ng < 4; ng++) {
          accx[rg][ng][r] *= fc;
          accy[rg][ng][r] *= fc;
        }
      }

    // ---- PV for both value streams ----
#pragma unroll
    for (int kk = 0; kk < 2; kk++) {
      half8 pa[2];
#pragma unroll
      for (int rg = 0; rg < 2; rg++)
        pa[rg] = *(const half8*)(Pw + (rg * 16 + lo) * 64 + (((kk * 4 + hi) ^ l7) << 3));
#pragma unroll
      for (int ng = 0; ng < 4; ng++) {
        const int vr = (ng * 16 + lo) * 64 + (((kk * 4 + hi) ^ l7) << 3);
        const half8 bv = *(const half8*)(Vb + vr);
        const half8 ba = *(const half8*)(Ab + vr);
#pragma unroll
        for (int rg = 0; rg < 2; rg++) {
          accx[rg][ng] = __builtin_amdgcn_mfma_f32_16x16x32_f16(pa[rg], bv, accx[rg][ng], 0, 0, 0);
          accy[rg][ng] = __builtin_amdgcn_mfma_f32_16x16x32_f16(pa[rg], ba, accy[rg][ng], 0, 0, 0);
        }
      }
    }
    bsel ^= 1;
  }
#undef STAGE

  // ---- normalize and store ----
#pragma unroll
  for (int rg = 0; rg < 2; rg++)
#pragma unroll
    for (int r = 0; r < 4; r++) {
      const float inv = 1.0f / lst[rg][r];
      const size_t tok = tokbase + q0 + rg * 16 + 4 * hi + r;
#pragma unroll
      for (int ng = 0; ng < 4; ng++) {
        const int col = h * DHEAD + ng * 16 + lo;
        xctx[tok * DM + col] = (_Float16)(accx[rg][ng][r] * inv);
        yctx[tok * DM + col] = (_Float16)(accy[rg][ng][r] * inv);
      }
    }
}

// ---------------- launch ----------------
extern "C" void kernel_launch(void* const* d_in, const int* in_sizes, int n_in,
                              void* d_out, int out_size, void* d_ws, size_t ws_size,
                              hipStream_t stream) {
  const float* x      = (const float*)d_in[0];
  const float* y      = (const float*)d_in[1];
  const float* ln_g   = (const float*)d_in[2];
  const float* ln_b   = (const float*)d_in[3];
  const float* w_qkv  = (const float*)d_in[4];
  const float* w_av   = (const float*)d_in[5];
  const float* w_out  = (const float*)d_in[6];
  const float* b_out  = (const float*)d_in[7];
  const float* w_yout = (const float*)d_in[8];
  const float* b_yout = (const float*)d_in[9];
  float* out = (float*)d_out;

  // workspace layout (f16 elements), ~76 MB
  _Float16* ws     = (_Float16*)d_ws;
  _Float16* xn     = ws;                 // 4096*1024
  _Float16* yh     = xn + 4194304;       // 4096*1024
  _Float16* wqkvT  = yh + 4194304;       // 3072*1024
  _Float16* wavT   = wqkvT + 3145728;    // 1024*1024
  _Float16* woutT  = wavT + 1048576;     // 1024*1024
  _Float16* wyoutT = woutT + 1048576;    // 1024*1024
  _Float16* qkvm   = wyoutT + 1048576;   // 4096*2048 (q|k)
  _Float16* vtb    = qkvm + 8388608;     // 32*64*2048
  _Float16* avtb   = vtb + 4194304;      // 32*64*2048
  _Float16* xc     = avtb + 4194304;     // 4096*1024
  _Float16* yc     = xc + 4194304;       // 4096*1024

  ln_cast_kernel<<<NTOK, 256, 0, stream>>>(x, ln_g, ln_b, xn);
  cast_f16_kernel<<<4096, 256, 0, stream>>>(y, yh);
  transpose_cast_kernel<<<dim3(48, 16), 256, 0, stream>>>(w_qkv, wqkvT, 1024, 3072);
  transpose_cast_kernel<<<dim3(16, 16), 256, 0, stream>>>(w_av, wavT, 1024, 1024);
  transpose_cast_kernel<<<dim3(16, 16), 256, 0, stream>>>(w_out, woutT, 1024, 1024);
  transpose_cast_kernel<<<dim3(16, 16), 256, 0, stream>>>(w_yout, wyoutT, 1024, 1024);

  // qkv (q,k normal @stride2048; v transposed to vtb) + av (all transposed to avtb)
  gemm2_kernel<0><<<1024, 256, 0, stream>>>(
      xn, wqkvT, qkvm, nullptr, nullptr, vtb, 2048, QKS, 24, 768,
      yh, wavT, qkvm, nullptr, nullptr, avtb, 0, QKS, 8);

  attn_kernel<<<512, 256, 0, stream>>>(qkvm, vtb, avtb, xc, yc);

  // two output projections fused in one launch (f32 + bias)
  gemm2_kernel<1><<<512, 256, 0, stream>>>(
      xc, woutT, nullptr, out, b_out, nullptr, 1 << 30, 1024, 8, 256,
      yc, wyoutT, nullptr, out + 4194304, b_yout, nullptr, 1 << 30, 1024, 8);
}

// Round 3
// 194.701 us; speedup vs baseline: 2.1285x; 1.3476x over previous
//
#include <hip/hip_runtime.h>

typedef _Float16 half8 __attribute__((ext_vector_type(8)));
typedef _Float16 half4v __attribute__((ext_vector_type(4)));
typedef float f32x4 __attribute__((ext_vector_type(4)));
typedef unsigned int u32;

#define SEQ 2048
#define NTOK 4096
#define DM 1024
#define QKS 2048
#define NHEAD 16
#define DHEAD 64
#define LN_EPS 1e-5f
#define LOG2E_SCALE 0.18033688f  // 0.125 * log2(e)

// ---------------- async global->LDS (16B per lane) ----------------
typedef const __attribute__((address_space(1))) u32* gas_ptr;
typedef __attribute__((address_space(3))) u32* las_ptr;
__device__ __forceinline__ void gld_lds16(const void* g, void* l) {
  __builtin_amdgcn_global_load_lds((gas_ptr)g, (las_ptr)l, 16, 0, 0);
}

// ---------------- LayerNorm + cast to f16 ----------------
__global__ __launch_bounds__(256) void ln_cast_kernel(
    const float* __restrict__ x, const float* __restrict__ g,
    const float* __restrict__ bta, _Float16* __restrict__ xn) {
  const int row = blockIdx.x;
  const int t = threadIdx.x;
  const float4 v = ((const float4*)(x + (size_t)row * DM))[t];
  float s = v.x + v.y + v.z + v.w;
#pragma unroll
  for (int m = 1; m < 64; m <<= 1) s += __shfl_xor(s, m, 64);
  __shared__ float red[4];
  const int wid = t >> 6, lane = t & 63;
  if (lane == 0) red[wid] = s;
  __syncthreads();
  const float mu = (red[0] + red[1] + red[2] + red[3]) * (1.0f / DM);
  const float dx = v.x - mu, dy = v.y - mu, dz = v.z - mu, dw = v.w - mu;
  float ss = dx * dx + dy * dy + dz * dz + dw * dw;
#pragma unroll
  for (int m = 1; m < 64; m <<= 1) ss += __shfl_xor(ss, m, 64);
  __syncthreads();
  if (lane == 0) red[wid] = ss;
  __syncthreads();
  const float var = (red[0] + red[1] + red[2] + red[3]) * (1.0f / DM);
  const float rstd = rsqrtf(var + LN_EPS);
  const float4 gg = ((const float4*)g)[t];
  const float4 bb = ((const float4*)bta)[t];
  half4v o;
  o[0] = (_Float16)(dx * rstd * gg.x + bb.x);
  o[1] = (_Float16)(dy * rstd * gg.y + bb.y);
  o[2] = (_Float16)(dz * rstd * gg.z + bb.z);
  o[3] = (_Float16)(dw * rstd * gg.w + bb.w);
  *(half4v*)(xn + (size_t)row * DM + t * 4) = o;
}

// ---------------- plain f32 -> f16 cast ----------------
__global__ __launch_bounds__(256) void cast_f16_kernel(const float* __restrict__ in,
                                                       _Float16* __restrict__ out) {
  const int i = blockIdx.x * 256 + threadIdx.x;
  const float4 v = ((const float4*)in)[i];
  half4v o;
  o[0] = (_Float16)v.x; o[1] = (_Float16)v.y;
  o[2] = (_Float16)v.z; o[3] = (_Float16)v.w;
  ((half4v*)out)[i] = o;
}

// ---------------- transpose + cast: W[K][Nc] f32 -> WT[Nc][K] f16 ----------------
__global__ __launch_bounds__(256) void transpose_cast_kernel(const float* __restrict__ W,
                                                             _Float16* __restrict__ WT,
                                                             int K, int Nc) {
  __shared__ float tile[64][65];
  const int n0 = blockIdx.x * 64, k0 = blockIdx.y * 64;
  const int t = threadIdx.x;
  const int c = t & 63;
#pragma unroll
  for (int i = 0; i < 16; i++) {
    const int r = (t >> 6) * 16 + i;
    tile[r][c] = W[(size_t)(k0 + r) * Nc + n0 + c];
  }
  __syncthreads();
#pragma unroll
  for (int i = 0; i < 16; i++) {
    const int n = (t >> 6) * 16 + i;
    WT[(size_t)(n0 + n) * K + k0 + c] = (_Float16)tile[c][n];
  }
}

// ---------------- fused-pair GEMM: C = A[M,1024] * BT[N,1024]^T ----------------
template <int OUTMODE>
__global__ __launch_bounds__(256) void gemm2_kernel(
    const _Float16* __restrict__ A0, const _Float16* __restrict__ B0,
    _Float16* C0, float* F0, const float* bias0, _Float16* T0, int trbase0, int cstr0,
    int nbx0, int nblk0,
    const _Float16* __restrict__ A1, const _Float16* __restrict__ B1,
    _Float16* C1, float* F1, const float* bias1, _Float16* T1, int trbase1, int cstr1,
    int nbx1) {
  __shared__ _Float16 As[128 * 32];
  __shared__ _Float16 Bs[128 * 32];
  int id = ((blockIdx.x & 7) * (gridDim.x >> 3)) + (blockIdx.x >> 3);
  const _Float16 *A, *BT;
  _Float16* Ch; float* Cf; const float* bias; _Float16* Ct;
  int trbase, cstr, nbx;
  if (id < nblk0) { A = A0; BT = B0; Ch = C0; Cf = F0; bias = bias0; Ct = T0; trbase = trbase0; cstr = cstr0; nbx = nbx0; }
  else { id -= nblk0; A = A1; BT = B1; Ch = C1; Cf = F1; bias = bias1; Ct = T1; trbase = trbase1; cstr = cstr1; nbx = nbx1; }
  const int bx = id % nbx, by = id / nbx;
  const int t = threadIdx.x;
  const int wid = t >> 6, lane = t & 63, lo = lane & 15, hi = lane >> 4;
  const int wm = wid >> 1, wn = wid & 1;
  const int m0 = by * 128, n0 = bx * 128;
  const int K = 1024;

  f32x4 zero;
  zero[0] = 0.f; zero[1] = 0.f; zero[2] = 0.f; zero[3] = 0.f;
  f32x4 acc[4][4];
#pragma unroll
  for (int i = 0; i < 4; i++)
#pragma unroll
    for (int j = 0; j < 4; j++) acc[i][j] = zero;

  const int rowA = t >> 2;
  const int kcol = (t & 3) * 8;
  const _Float16* gA = A + (size_t)(m0 + rowA) * K + kcol;
  const _Float16* gB = BT + (size_t)(n0 + rowA) * K + kcol;

  for (int k0 = 0; k0 < K; k0 += 32) {
#pragma unroll
    for (int j = 0; j < 2; j++) {
      gld_lds16(gA + (size_t)(j * 64) * K + k0, As + j * 2048 + wid * 512);
      gld_lds16(gB + (size_t)(j * 64) * K + k0, Bs + j * 2048 + wid * 512);
    }
    __syncthreads();
    half8 af[4], bf[4];
#pragma unroll
    for (int i = 0; i < 4; i++) {
      af[i] = *(const half8*)(As + (wm * 64 + i * 16 + lo) * 32 + hi * 8);
      bf[i] = *(const half8*)(Bs + (wn * 64 + i * 16 + lo) * 32 + hi * 8);
    }
#pragma unroll
    for (int i = 0; i < 4; i++)
#pragma unroll
      for (int j = 0; j < 4; j++)
        acc[i][j] = __builtin_amdgcn_mfma_f32_16x16x32_f16(af[i], bf[j], acc[i][j], 0, 0, 0);
    __syncthreads();
  }

  if (OUTMODE == 1) {
#pragma unroll
    for (int i = 0; i < 4; i++)
#pragma unroll
      for (int j = 0; j < 4; j++)
#pragma unroll
        for (int r = 0; r < 4; r++) {
          const int row = m0 + wm * 64 + i * 16 + 4 * hi + r;
          const int col = n0 + wn * 64 + j * 16 + lo;
          Cf[(size_t)row * cstr + col] = acc[i][j][r] + bias[col];
        }
  } else if (n0 >= trbase) {
#pragma unroll
    for (int i = 0; i < 4; i++)
#pragma unroll
      for (int j = 0; j < 4; j++)
#pragma unroll
        for (int r = 0; r < 4; r++) {
          const int row = m0 + wm * 64 + i * 16 + 4 * hi + r;
          const int coff = n0 + wn * 64 + j * 16 + lo - trbase;
          Ct[(((size_t)((row >> 11) << 4) + (coff >> 6)) * 64 + (coff & 63)) * SEQ +
             (row & (SEQ - 1))] = (_Float16)acc[i][j][r];
        }
  } else {
#pragma unroll
    for (int i = 0; i < 4; i++)
#pragma unroll
      for (int j = 0; j < 4; j++)
#pragma unroll
        for (int r = 0; r < 4; r++) {
          const int row = m0 + wm * 64 + i * 16 + 4 * hi + r;
          const int col = n0 + wn * 64 + j * 16 + lo;
          Ch[(size_t)row * cstr + col] = (_Float16)acc[i][j][r];
        }
  }
}

// ---------------- fused flash attention, two value streams ----------------
// Swapped QK^T (mfma(K,Q) -> S^T[key][query]): in-lane softmax, packed b64
// P writes, defer-max rescale. 512 blocks, 4 waves, wave owns 32 q-rows.
__global__ __launch_bounds__(256) void attn_kernel(
    const _Float16* __restrict__ qkvm,  // [NTOK][2048]: q | k
    const _Float16* __restrict__ vt,    // [32][64][SEQ]
    const _Float16* __restrict__ avt,   // [32][64][SEQ]
    _Float16* __restrict__ xctx, _Float16* __restrict__ yctx) {
  __shared__ _Float16 Kl[2][4096];
  __shared__ _Float16 Vl[2][4096];
  __shared__ _Float16 Al[2][4096];
  __shared__ _Float16 Pl[4][2048];

  const int t = threadIdx.x;
  const int wid = t >> 6, lane = t & 63, lo = lane & 15, hi = lane >> 4;
  const int l7 = lane & 7;
  const int id = blockIdx.x;
  const int bh = ((id & 7) << 2) + ((id >> 3) >> 4);
  const int qt = (id >> 3) & 15;
  const int b = bh >> 4, h = bh & 15;
  const int q0 = qt * 128 + wid * 32;
  const size_t tokbase = (size_t)b * SEQ;
  const _Float16* vbase = vt + (size_t)bh * DHEAD * SEQ;
  const _Float16* abase = avt + (size_t)bh * DHEAD * SEQ;

  // Q as B-fragment: lane holds Q[q0+rg*16+lo][kc*32 + hi*8 .. +7]
  half8 qf[2][2];
#pragma unroll
  for (int rg = 0; rg < 2; rg++)
#pragma unroll
    for (int kc = 0; kc < 2; kc++)
      qf[rg][kc] = *(const half8*)(qkvm + (tokbase + q0 + rg * 16 + lo) * QKS +
                                   h * DHEAD + kc * 32 + hi * 8);

  f32x4 zero;
  zero[0] = 0.f; zero[1] = 0.f; zero[2] = 0.f; zero[3] = 0.f;
  f32x4 accx[2][4], accy[2][4];
  float mC[2], lsum[2];  // per-lane state for query rg*16+lo (scaled log2 domain)
#pragma unroll
  for (int rg = 0; rg < 2; rg++) {
#pragma unroll
    for (int j = 0; j < 4; j++) { accx[rg][j] = zero; accy[rg][j] = zero; }
    mC[rg] = -1.0e30f; lsum[rg] = 0.0f;
  }

  const int skey = t >> 3;  // 0..31
  const int sc7 = t & 7;

#define STAGE(kv0, bsel)                                                          \
  do {                                                                            \
    _Pragma("unroll") for (int j = 0; j < 2; j++) {                               \
      const int key = skey + j * 32;                                              \
      const int cs = ((sc7 ^ (key & 7)) << 3);                                    \
      gld_lds16(qkvm + (tokbase + (kv0) + key) * QKS + DM + h * DHEAD + cs,       \
                &Kl[bsel][j * 2048 + wid * 512]);                                 \
      gld_lds16(vbase + (size_t)key * SEQ + (kv0) + cs,                           \
                &Vl[bsel][j * 2048 + wid * 512]);                                 \
      gld_lds16(abase + (size_t)key * SEQ + (kv0) + cs,                           \
                &Al[bsel][j * 2048 + wid * 512]);                                 \
    }                                                                             \
  } while (0)

  STAGE(0, 0);
  int bsel = 0;
  for (int tt = 0; tt < SEQ / 64; tt++) {
    __syncthreads();  // tile tt staged
    if (tt + 1 < SEQ / 64) STAGE((tt + 1) * 64, bsel ^ 1);
    const _Float16* Kb = Kl[bsel];
    const _Float16* Vb = Vl[bsel];
    const _Float16* Ab = Al[bsel];
    _Float16* Pw = Pl[wid];

    // ---- S^T = K Q^T : s[rg][kg], row(key)=4*hi+r, col(query)=lo ----
    f32x4 s[2][4];
#pragma unroll
    for (int kg = 0; kg < 4; kg++) {
      const int kr = (kg * 16 + lo) * 64;
      const half8 ak0 = *(const half8*)(Kb + kr + ((hi ^ l7) << 3));
      const half8 ak1 = *(const half8*)(Kb + kr + (((4 | hi) ^ l7) << 3));
#pragma unroll
      for (int rg = 0; rg < 2; rg++) {
        f32x4 z = __builtin_amdgcn_mfma_f32_16x16x32_f16(ak0, qf[rg][0], zero, 0, 0, 0);
        s[rg][kg] = __builtin_amdgcn_mfma_f32_16x16x32_f16(ak1, qf[rg][1], z, 0, 0, 0);
      }
    }

    // ---- in-lane tile max (16 vals) + 2-step cross-lane (hi dim) ----
    float tmC[2];
#pragma unroll
    for (int rg = 0; rg < 2; rg++) {
      float tm = -3.0e38f;
#pragma unroll
      for (int kg = 0; kg < 4; kg++)
#pragma unroll
        for (int r = 0; r < 4; r++) tm = fmaxf(tm, s[rg][kg][r]);
      tm = fmaxf(tm, __shfl_xor(tm, 16, 64));
      tm = fmaxf(tm, __shfl_xor(tm, 32, 64));
      tmC[rg] = tm * LOG2E_SCALE;
    }

    // ---- defer-max: rescale only when max grows past threshold ----
    const bool grow = (tmC[0] > mC[0] + 8.0f) | (tmC[1] > mC[1] + 8.0f);
    if (__any(grow)) {
      float fcs[2];
#pragma unroll
      for (int rg = 0; rg < 2; rg++) {
        const float mn = fmaxf(mC[rg], tmC[rg]);
        fcs[rg] = exp2f(mC[rg] - mn);
        mC[rg] = mn;
        lsum[rg] *= fcs[rg];
      }
#pragma unroll
      for (int rg = 0; rg < 2; rg++)
#pragma unroll
        for (int r = 0; r < 4; r++) {
          const float fcb = __shfl(fcs[rg], 4 * hi + r, 64);
#pragma unroll
          for (int ng = 0; ng < 4; ng++) {
            accx[rg][ng][r] *= fcb;
            accy[rg][ng][r] *= fcb;
          }
        }
    }

    // ---- P = exp2(s*C - mC), in-lane sum, packed b64 write ----
#pragma unroll
    for (int rg = 0; rg < 2; rg++) {
      float rs = 0.0f;
#pragma unroll
      for (int kg = 0; kg < 4; kg++) {
        half4v pk;
#pragma unroll
        for (int r = 0; r < 4; r++) {
          const float p = exp2f(fmaf(s[rg][kg][r], LOG2E_SCALE, -mC[rg]));
          rs += p;
          pk[r] = (_Float16)p;
        }
        // keys kg*16+4*hi+r live in data-chunk kg*2+(hi>>1), stored at chunk^row&7
        *(half4v*)(Pw + (rg * 16 + lo) * 64 +
                   (((kg * 2 + (hi >> 1)) ^ l7) << 3) + ((hi & 1) << 2)) = pk;
      }
      rs += __shfl_xor(rs, 16, 64);
      rs += __shfl_xor(rs, 32, 64);
      lsum[rg] += rs;
    }

    // ---- PV for both value streams ----
#pragma unroll
    for (int kk = 0; kk < 2; kk++) {
      half8 pa[2];
#pragma unroll
      for (int rg = 0; rg < 2; rg++)
        pa[rg] = *(const half8*)(Pw + (rg * 16 + lo) * 64 + (((kk * 4 + hi) ^ l7) << 3));
#pragma unroll
      for (int ng = 0; ng < 4; ng++) {
        const int vr = (ng * 16 + lo) * 64 + (((kk * 4 + hi) ^ l7) << 3);
        const half8 bv = *(const half8*)(Vb + vr);
        const half8 ba = *(const half8*)(Ab + vr);
#pragma unroll
        for (int rg = 0; rg < 2; rg++) {
          accx[rg][ng] = __builtin_amdgcn_mfma_f32_16x16x32_f16(pa[rg], bv, accx[rg][ng], 0, 0, 0);
          accy[rg][ng] = __builtin_amdgcn_mfma_f32_16x16x32_f16(pa[rg], ba, accy[rg][ng], 0, 0, 0);
        }
      }
    }
    bsel ^= 1;
  }
#undef STAGE

  // ---- normalize (broadcast 1/l to acc rows) and store ----
#pragma unroll
  for (int rg = 0; rg < 2; rg++) {
    const float inv = 1.0f / lsum[rg];
#pragma unroll
    for (int r = 0; r < 4; r++) {
      const float invb = __shfl(inv, 4 * hi + r, 64);
      const size_t tok = tokbase + q0 + rg * 16 + 4 * hi + r;
#pragma unroll
      for (int ng = 0; ng < 4; ng++) {
        const int col = h * DHEAD + ng * 16 + lo;
        xctx[tok * DM + col] = (_Float16)(accx[rg][ng][r] * invb);
        yctx[tok * DM + col] = (_Float16)(accy[rg][ng][r] * invb);
      }
    }
  }
}

// ---------------- launch ----------------
extern "C" void kernel_launch(void* const* d_in, const int* in_sizes, int n_in,
                              void* d_out, int out_size, void* d_ws, size_t ws_size,
                              hipStream_t stream) {
  const float* x      = (const float*)d_in[0];
  const float* y      = (const float*)d_in[1];
  const float* ln_g   = (const float*)d_in[2];
  const float* ln_b   = (const float*)d_in[3];
  const float* w_qkv  = (const float*)d_in[4];
  const float* w_av   = (const float*)d_in[5];
  const float* w_out  = (const float*)d_in[6];
  const float* b_out  = (const float*)d_in[7];
  const float* w_yout = (const float*)d_in[8];
  const float* b_yout = (const float*)d_in[9];
  float* out = (float*)d_out;

  _Float16* ws     = (_Float16*)d_ws;
  _Float16* xn     = ws;                 // 4096*1024
  _Float16* yh     = xn + 4194304;       // 4096*1024
  _Float16* wqkvT  = yh + 4194304;       // 3072*1024
  _Float16* wavT   = wqkvT + 3145728;    // 1024*1024
  _Float16* woutT  = wavT + 1048576;     // 1024*1024
  _Float16* wyoutT = woutT + 1048576;    // 1024*1024
  _Float16* qkvm   = wyoutT + 1048576;   // 4096*2048 (q|k)
  _Float16* vtb    = qkvm + 8388608;     // 32*64*2048
  _Float16* avtb   = vtb + 4194304;      // 32*64*2048
  _Float16* xc     = avtb + 4194304;     // 4096*1024
  _Float16* yc     = xc + 4194304;       // 4096*1024

  ln_cast_kernel<<<NTOK, 256, 0, stream>>>(x, ln_g, ln_b, xn);
  cast_f16_kernel<<<4096, 256, 0, stream>>>(y, yh);
  transpose_cast_kernel<<<dim3(48, 16), 256, 0, stream>>>(w_qkv, wqkvT, 1024, 3072);
  transpose_cast_kernel<<<dim3(16, 16), 256, 0, stream>>>(w_av, wavT, 1024, 1024);
  transpose_cast_kernel<<<dim3(16, 16), 256, 0, stream>>>(w_out, woutT, 1024, 1024);
  transpose_cast_kernel<<<dim3(16, 16), 256, 0, stream>>>(w_yout, wyoutT, 1024, 1024);

  gemm2_kernel<0><<<1024, 256, 0, stream>>>(
      xn, wqkvT, qkvm, nullptr, nullptr, vtb, 2048, QKS, 24, 768,
      yh, wavT, qkvm, nullptr, nullptr, avtb, 0, QKS, 8);

  attn_kernel<<<512, 256, 0, stream>>>(qkvm, vtb, avtb, xc, yc);

  gemm2_kernel<1><<<512, 256, 0, stream>>>(
      xc, woutT, nullptr, out, b_out, nullptr, 1 << 30, 1024, 8, 256,
      yc, wyoutT, nullptr, out + 4194304, b_yout, nullptr, 1 << 30, 1024, 8);
}